// Round 1
// baseline (80.075 us; speedup 1.0000x reference)
//
#include <hip/hip_runtime.h>
#include <math.h>

// KDE: out[m] = exp(t1)/N * sum_n exp( (dot(xe_m,xb_n) - 0.5*|xe_m|^2 - 0.5*|xb_n|^2) / bw^2 )
// computed in the log2 domain with v_exp_f32.

#define LOG_2PI_F 1.8378770664093453f
#define LOG2E_F   1.4426950408889634f

#define M_PTS 8192
#define N_PTS 16384
#define D_DIM 16
#define BM 64          // eval rows per block
#define BN 64          // base rows per LDS tile
#define NCHUNK 8       // N split across blockIdx.y
#define CHUNK (N_PTS / NCHUNK)   // 2048

// ---------------------------------------------------------------------------
// kernel 0: cb[n] = -0.5 * |xb_n|^2 / bw2 * log2(e)
__global__ __launch_bounds__(256) void kde_prep(const float* __restrict__ xb,
                                                const float* __restrict__ log_bw,
                                                float* __restrict__ cb) {
    int n = blockIdx.x * 256 + threadIdx.x;
    if (n >= N_PTS) return;
    float lb = log_bw[0];
    float inv_bw2 = __expf(-2.0f * lb);
    const float4* row = (const float4*)(xb + (size_t)n * D_DIM);
    float s = 0.f;
#pragma unroll
    for (int k = 0; k < 4; ++k) {
        float4 v = row[k];
        s = fmaf(v.x, v.x, s); s = fmaf(v.y, v.y, s);
        s = fmaf(v.z, v.z, s); s = fmaf(v.w, v.w, s);
    }
    cb[n] = -0.5f * s * inv_bw2 * LOG2E_F;
}

// ---------------------------------------------------------------------------
// main: block handles BM eval rows x CHUNK base points; partial sums to ws.
__global__ __launch_bounds__(256) void kde_main(const float* __restrict__ xe,
                                                const float* __restrict__ xb,
                                                const float* __restrict__ log_bw,
                                                const float* __restrict__ cb,
                                                float* __restrict__ part) {
    // seg-major float4 layout: row stride = 16B -> consecutive rows hit
    // consecutive 4-bank groups; read rows are tx+16j (stride-1 in tx) ->
    // 8 bank-groups covered, b128 floor, no serialization.
    __shared__ float4 Bs4[4][BN + 1];
    __shared__ float  cbs[BN];
    __shared__ float  red[BM][17];

    const int tid = threadIdx.x;
    const int tx = tid & 15;        // base-point lane group
    const int ty = tid >> 4;        // eval-row group (16 groups of 4 rows)
    const int m0 = blockIdx.x * BM;
    const int chunk = blockIdx.y;

    const float lb = log_bw[0];
    const float inv_bw2 = __expf(-2.0f * lb);
    const float k2 = LOG2E_F * inv_bw2;     // multiplies the dot product

    // 4 eval rows in registers, reused for all 2048 base points
    float4 a[4][4];
    float  ce[4];
#pragma unroll
    for (int i = 0; i < 4; ++i) {
        const float4* row = (const float4*)(xe + (size_t)(m0 + ty * 4 + i) * D_DIM);
        float s = 0.f;
#pragma unroll
        for (int k = 0; k < 4; ++k) {
            float4 v = row[k];
            a[i][k] = v;
            s = fmaf(v.x, v.x, s); s = fmaf(v.y, v.y, s);
            s = fmaf(v.z, v.z, s); s = fmaf(v.w, v.w, s);
        }
        ce[i] = -0.5f * s * k2;   // -0.5*|xe|^2/bw2*log2e
    }

    float acc[4] = {0.f, 0.f, 0.f, 0.f};
    const int n_base = chunk * CHUNK;

    for (int t0 = 0; t0 < CHUNK; t0 += BN) {
        __syncthreads();
        {   // stage 64 base rows: thread -> (row r, segment s), coalesced 1KB/wave
            int r = tid >> 2, s = tid & 3;
            Bs4[s][r] = ((const float4*)xb)[(size_t)(n_base + t0 + r) * 4 + s];
            if (tid < BN) cbs[tid] = cb[n_base + t0 + tid];
        }
        __syncthreads();

#pragma unroll
        for (int j = 0; j < 4; ++j) {
            const int r = tx + 16 * j;
            const float4 b0 = Bs4[0][r];
            const float4 b1 = Bs4[1][r];
            const float4 b2 = Bs4[2][r];
            const float4 b3 = Bs4[3][r];
            const float cbj = cbs[r];
#pragma unroll
            for (int i = 0; i < 4; ++i) {
                float d;
                d = a[i][0].x * b0.x;
                d = fmaf(a[i][0].y, b0.y, d);
                d = fmaf(a[i][0].z, b0.z, d);
                d = fmaf(a[i][0].w, b0.w, d);
                d = fmaf(a[i][1].x, b1.x, d);
                d = fmaf(a[i][1].y, b1.y, d);
                d = fmaf(a[i][1].z, b1.z, d);
                d = fmaf(a[i][1].w, b1.w, d);
                d = fmaf(a[i][2].x, b2.x, d);
                d = fmaf(a[i][2].y, b2.y, d);
                d = fmaf(a[i][2].z, b2.z, d);
                d = fmaf(a[i][2].w, b2.w, d);
                d = fmaf(a[i][3].x, b3.x, d);
                d = fmaf(a[i][3].y, b3.y, d);
                d = fmaf(a[i][3].z, b3.z, d);
                d = fmaf(a[i][3].w, b3.w, d);
                float arg = fmaf(d, k2, ce[i] + cbj);   // t2 * log2(e), <= ~0
                acc[i] += __builtin_amdgcn_exp2f(arg);  // v_exp_f32
            }
        }
    }

    // reduce acc across the 16 tx lanes per eval row
#pragma unroll
    for (int i = 0; i < 4; ++i) red[ty * 4 + i][tx] = acc[i];
    __syncthreads();
    if (tid < BM) {
        float s = 0.f;
#pragma unroll
        for (int x = 0; x < 16; ++x) s += red[tid][x];
        part[(size_t)chunk * M_PTS + m0 + tid] = s;
    }
}

// ---------------------------------------------------------------------------
// reduce over the NCHUNK partials, apply exp(t1)/N
__global__ __launch_bounds__(256) void kde_reduce(const float* __restrict__ part,
                                                  const float* __restrict__ log_bw,
                                                  float* __restrict__ out) {
    int m = blockIdx.x * 256 + threadIdx.x;
    if (m >= M_PTS) return;
    float lb = log_bw[0];
    float t1 = -8.0f * LOG_2PI_F - lb;             // -0.5*D*log(2pi) - log_bw
    float scale = __expf(t1) / (float)N_PTS;
    float s = 0.f;
#pragma unroll
    for (int c = 0; c < NCHUNK; ++c) s += part[(size_t)c * M_PTS + m];
    out[m] = scale * s;
}

// ---------------------------------------------------------------------------
extern "C" void kernel_launch(void* const* d_in, const int* in_sizes, int n_in,
                              void* d_out, int out_size, void* d_ws, size_t ws_size,
                              hipStream_t stream) {
    const float* xe = (const float*)d_in[0];     // [8192,16]
    const float* xb = (const float*)d_in[1];     // [16384,16]
    const float* lb = (const float*)d_in[2];     // [1]
    float* out = (float*)d_out;                  // [8192]

    float* cb   = (float*)d_ws;                  // N_PTS floats
    float* part = cb + N_PTS;                    // NCHUNK*M_PTS floats (~320KB total)

    kde_prep<<<N_PTS / 256, 256, 0, stream>>>(xb, lb, cb);
    dim3 grid(M_PTS / BM, NCHUNK);
    kde_main<<<grid, 256, 0, stream>>>(xe, xb, lb, cb, part);
    kde_reduce<<<M_PTS / 256, 256, 0, stream>>>(part, lb, out);
}

// Round 2
// 51.338 us; speedup vs baseline: 1.5597x; 1.5597x over previous
//
#include <hip/hip_runtime.h>
#include <math.h>

// KDE via bf16 hi/lo split MFMA:
//   dot(e,b) - 0.5|e|^2 - 0.5|b|^2  computed by 4x mfma_f32_32x32x16_bf16:
//     hh + hl + lh  (data)  +  norms MFMA ([cbh,cbl,1,1] x [1,1,ceh,cel])
//   then arg = C * (inv_bw2*log2e); acc += exp2(arg); scale at the end.

#define LOG_2PI_F 1.8378770664093453f
#define LOG2E_F   1.4426950408889634f

#define M_PTS 8192
#define N_PTS 16384

typedef __attribute__((ext_vector_type(8)))  short bf16x8;
typedef __attribute__((ext_vector_type(16))) float f32x16;

static __device__ __forceinline__ unsigned short f2bf(float x) {
    unsigned u = __float_as_uint(x);
    u += 0x7fffu + ((u >> 16) & 1u);          // RNE
    return (unsigned short)(u >> 16);
}
static __device__ __forceinline__ float bf2f(unsigned short h) {
    return __uint_as_float(((unsigned)h) << 16);
}
static __device__ __forceinline__ uint4 pack8(const unsigned short* a) {
    uint4 u;
    u.x = (unsigned)a[0] | ((unsigned)a[1] << 16);
    u.y = (unsigned)a[2] | ((unsigned)a[3] << 16);
    u.z = (unsigned)a[4] | ((unsigned)a[5] << 16);
    u.w = (unsigned)a[6] | ((unsigned)a[7] << 16);
    return u;
}

// ---------------------------------------------------------------------------
// pack: x -> bf16 hi, bf16 lo, and norm-slot row.
//   base rows:  pn = [cbh, cbl, 1, 1, 0...]   (cb = -0.5|x|^2)
//   eval rows:  pn = [1, 1, ceh, cel, 0...]
__global__ __launch_bounds__(256) void kde_pack(
        const float* __restrict__ x, int rows, int is_eval,
        unsigned short* __restrict__ ph, unsigned short* __restrict__ pl,
        unsigned short* __restrict__ pn) {
    int r = blockIdx.x * 256 + threadIdx.x;
    if (r >= rows) return;
    const float4* row = (const float4*)(x + (size_t)r * 16);
    unsigned short hs[16], ls[16], ns[16];
    float s = 0.f;
#pragma unroll
    for (int k = 0; k < 4; ++k) {
        float4 v = row[k];
        float c0 = v.x, c1 = v.y, c2 = v.z, c3 = v.w;
        unsigned short h;
        h = f2bf(c0); hs[k*4+0] = h; ls[k*4+0] = f2bf(c0 - bf2f(h)); s = fmaf(c0, c0, s);
        h = f2bf(c1); hs[k*4+1] = h; ls[k*4+1] = f2bf(c1 - bf2f(h)); s = fmaf(c1, c1, s);
        h = f2bf(c2); hs[k*4+2] = h; ls[k*4+2] = f2bf(c2 - bf2f(h)); s = fmaf(c2, c2, s);
        h = f2bf(c3); hs[k*4+3] = h; ls[k*4+3] = f2bf(c3 - bf2f(h)); s = fmaf(c3, c3, s);
    }
    float cb = -0.5f * s;
    unsigned short ch = f2bf(cb);
    unsigned short cl = f2bf(cb - bf2f(ch));
#pragma unroll
    for (int i = 0; i < 16; ++i) ns[i] = 0;
    if (is_eval) { ns[0] = 0x3F80; ns[1] = 0x3F80; ns[2] = ch;     ns[3] = cl; }
    else         { ns[0] = ch;     ns[1] = cl;     ns[2] = 0x3F80; ns[3] = 0x3F80; }

    uint4* dh = (uint4*)(ph + (size_t)r * 16);
    uint4* dl = (uint4*)(pl + (size_t)r * 16);
    uint4* dn = (uint4*)(pn + (size_t)r * 16);
    dh[0] = pack8(hs); dh[1] = pack8(hs + 8);
    dl[0] = pack8(ls); dl[1] = pack8(ls + 8);
    dn[0] = pack8(ns); dn[1] = pack8(ns + 8);
}

// ---------------------------------------------------------------------------
// main: wave owns 2 eval tiles (64 eval rows) x one base chunk (512 base rows).
// A = base (rows), B = eval (cols). D layout: col=lane&31, row covered by regs.
__global__ __launch_bounds__(256) void kde_mfma(
        const unsigned short* __restrict__ eh, const unsigned short* __restrict__ el,
        const unsigned short* __restrict__ en,
        const unsigned short* __restrict__ bh, const unsigned short* __restrict__ bl,
        const unsigned short* __restrict__ bn,
        const float* __restrict__ log_bw, float* __restrict__ part) {
    const int lane = threadIdx.x & 63;
    const int w = blockIdx.x * 4 + (threadIdx.x >> 6);   // 0..4095
    const int chunk = w >> 7;                            // 0..31 (block-shared)
    const int etp   = w & 127;                           // 0..127: 64 eval rows
    const int col   = lane & 31;
    const int kg    = lane >> 5;

    const float k2l = __expf(-2.f * log_bw[0]) * LOG2E_F;

    // eval (B) fragments for both tiles — resident for whole kernel
    size_t e0 = ((size_t)etp * 64 + col) * 16 + (size_t)kg * 8;
    size_t e1 = e0 + 32 * 16;
    const bf16x8 Bh0 = *(const bf16x8*)(eh + e0);
    const bf16x8 Bl0 = *(const bf16x8*)(el + e0);
    const bf16x8 Bn0 = *(const bf16x8*)(en + e0);
    const bf16x8 Bh1 = *(const bf16x8*)(eh + e1);
    const bf16x8 Bl1 = *(const bf16x8*)(el + e1);
    const bf16x8 Bn1 = *(const bf16x8*)(en + e1);

    // base (A) pointers: 16 tiles of 32 rows each
    size_t aoff = ((size_t)chunk * 512 + col) * 16 + (size_t)kg * 8;
    const unsigned short* pah = bh + aoff;
    const unsigned short* pal = bl + aoff;
    const unsigned short* pan = bn + aoff;

    float a00 = 0.f, a01 = 0.f, a10 = 0.f, a11 = 0.f;

    for (int t = 0; t < 16; ++t) {
        const bf16x8 Ah = *(const bf16x8*)pah;
        const bf16x8 Al = *(const bf16x8*)pal;
        const bf16x8 An = *(const bf16x8*)pan;
        pah += 32 * 16; pal += 32 * 16; pan += 32 * 16;

        f32x16 C0, C1;
#pragma unroll
        for (int r = 0; r < 16; ++r) { C0[r] = 0.f; C1[r] = 0.f; }
        C0 = __builtin_amdgcn_mfma_f32_32x32x16_bf16(Ah, Bh0, C0, 0, 0, 0);
        C0 = __builtin_amdgcn_mfma_f32_32x32x16_bf16(Ah, Bl0, C0, 0, 0, 0);
        C0 = __builtin_amdgcn_mfma_f32_32x32x16_bf16(Al, Bh0, C0, 0, 0, 0);
        C0 = __builtin_amdgcn_mfma_f32_32x32x16_bf16(An, Bn0, C0, 0, 0, 0);
        C1 = __builtin_amdgcn_mfma_f32_32x32x16_bf16(Ah, Bh1, C1, 0, 0, 0);
        C1 = __builtin_amdgcn_mfma_f32_32x32x16_bf16(Ah, Bl1, C1, 0, 0, 0);
        C1 = __builtin_amdgcn_mfma_f32_32x32x16_bf16(Al, Bh1, C1, 0, 0, 0);
        C1 = __builtin_amdgcn_mfma_f32_32x32x16_bf16(An, Bn1, C1, 0, 0, 0);

#pragma unroll
        for (int r = 0; r < 16; r += 2) {
            a00 += __builtin_amdgcn_exp2f(C0[r]     * k2l);
            a01 += __builtin_amdgcn_exp2f(C0[r + 1] * k2l);
            a10 += __builtin_amdgcn_exp2f(C1[r]     * k2l);
            a11 += __builtin_amdgcn_exp2f(C1[r + 1] * k2l);
        }
    }

    float s0 = a00 + a01;
    float s1 = a10 + a11;
    s0 += __shfl_xor(s0, 32, 64);   // fold the two kg row-groups
    s1 += __shfl_xor(s1, 32, 64);
    if (lane < 32) {
        float* p = part + (size_t)chunk * M_PTS + (size_t)etp * 64;
        p[col]      = s0;
        p[32 + col] = s1;
    }
}

// ---------------------------------------------------------------------------
__global__ __launch_bounds__(256) void kde_reduce(
        const float* __restrict__ part, const float* __restrict__ log_bw,
        float* __restrict__ out) {
    int m = blockIdx.x * 256 + threadIdx.x;
    if (m >= M_PTS) return;
    float lb = log_bw[0];
    float scale = __expf(-8.f * LOG_2PI_F - lb) / (float)N_PTS;
    float s = 0.f;
#pragma unroll
    for (int c = 0; c < 32; ++c) s += part[(size_t)c * M_PTS + m];
    out[m] = scale * s;
}

// ---------------------------------------------------------------------------
extern "C" void kernel_launch(void* const* d_in, const int* in_sizes, int n_in,
                              void* d_out, int out_size, void* d_ws, size_t ws_size,
                              hipStream_t stream) {
    const float* xe = (const float*)d_in[0];   // [8192,16]
    const float* xb = (const float*)d_in[1];   // [16384,16]
    const float* lb = (const float*)d_in[2];   // [1]
    float* out = (float*)d_out;                // [8192]

    unsigned short* w0 = (unsigned short*)d_ws;
    unsigned short* bh = w0;
    unsigned short* bl = bh + (size_t)N_PTS * 16;
    unsigned short* bn = bl + (size_t)N_PTS * 16;
    unsigned short* eh = bn + (size_t)N_PTS * 16;
    unsigned short* el = eh + (size_t)M_PTS * 16;
    unsigned short* en = el + (size_t)M_PTS * 16;
    float* part = (float*)(en + (size_t)M_PTS * 16);   // 32*8192 floats

    kde_pack<<<N_PTS / 256, 256, 0, stream>>>(xb, N_PTS, 0, bh, bl, bn);
    kde_pack<<<M_PTS / 256, 256, 0, stream>>>(xe, M_PTS, 1, eh, el, en);
    kde_mfma<<<1024, 256, 0, stream>>>(eh, el, en, bh, bl, bn, lb, part);
    kde_reduce<<<M_PTS / 256, 256, 0, stream>>>(part, lb, out);
}

// Round 3
// 47.682 us; speedup vs baseline: 1.6794x; 1.0767x over previous
//
#include <hip/hip_runtime.h>
#include <math.h>

// KDE via bf16 hi/lo split MFMA, prescaled so the inner loop is exp2(C)+add.
//   arg = k2l*(dot(e,b) - 0.5|e|^2 - 0.5|b|^2),  k2l = exp(-2 log_bw)*log2(e)
//   eval vectors prescaled by k2l; norms prescaled; per tile:
//     C = Ah*Bh + Ah*Bl + Al*Bh + An*Bn   (An/Bn carry the norm constants)
//   out[m] = exp(t1)/N * sum exp2(C)

#define LOG_2PI_F 1.8378770664093453f
#define LOG2E_F   1.4426950408889634f

#define M_PTS 8192
#define N_PTS 16384
#define NCH   64                      // N chunks
#define ROWS_PER_CHUNK (N_PTS / NCH)  // 256
#define TPC (ROWS_PER_CHUNK / 32)     // 8 A-tiles per chunk

typedef __attribute__((ext_vector_type(8)))  short bf16x8;
typedef __attribute__((ext_vector_type(16))) float f32x16;

static __device__ __forceinline__ unsigned short f2bf(float x) {
    unsigned u = __float_as_uint(x);
    u += 0x7fffu + ((u >> 16) & 1u);          // RNE
    return (unsigned short)(u >> 16);
}
static __device__ __forceinline__ float bf2f(unsigned short h) {
    return __uint_as_float(((unsigned)h) << 16);
}
static __device__ __forceinline__ uint4 pack8(const unsigned short* a) {
    uint4 u;
    u.x = (unsigned)a[0] | ((unsigned)a[1] << 16);
    u.y = (unsigned)a[2] | ((unsigned)a[3] << 16);
    u.z = (unsigned)a[4] | ((unsigned)a[5] << 16);
    u.w = (unsigned)a[6] | ((unsigned)a[7] << 16);
    return u;
}

// ---------------------------------------------------------------------------
// merged pack: r < N_PTS -> base row (data unscaled, norm scaled by k2l)
//              else      -> eval row (data AND norm scaled by k2l)
__global__ __launch_bounds__(256) void kde_pack(
        const float* __restrict__ xe, const float* __restrict__ xb,
        const float* __restrict__ log_bw,
        unsigned short* __restrict__ bh, unsigned short* __restrict__ bl,
        unsigned short* __restrict__ bn,
        unsigned short* __restrict__ eh, unsigned short* __restrict__ el,
        unsigned short* __restrict__ en) {
    int r = blockIdx.x * 256 + threadIdx.x;
    if (r >= N_PTS + M_PTS) return;
    const float k2l = __expf(-2.f * log_bw[0]) * LOG2E_F;

    int is_eval = (r >= N_PTS);
    int rr = is_eval ? (r - N_PTS) : r;
    const float* src = is_eval ? xe : xb;
    float dscale = is_eval ? k2l : 1.0f;       // eval data prescaled

    const float4* row = (const float4*)(src + (size_t)rr * 16);
    unsigned short hs[16], ls[16], ns[16];
    float s = 0.f;
#pragma unroll
    for (int k = 0; k < 4; ++k) {
        float4 v = row[k];
        float c[4] = {v.x, v.y, v.z, v.w};
#pragma unroll
        for (int j = 0; j < 4; ++j) {
            s = fmaf(c[j], c[j], s);
            float d = c[j] * dscale;
            unsigned short h = f2bf(d);
            hs[k*4+j] = h;
            ls[k*4+j] = f2bf(d - bf2f(h));
        }
    }
    float cn = -0.5f * s * k2l;                // scaled norm constant
    unsigned short ch = f2bf(cn);
    unsigned short cl = f2bf(cn - bf2f(ch));
#pragma unroll
    for (int i = 0; i < 16; ++i) ns[i] = 0;
    if (is_eval) { ns[0] = 0x3F80; ns[1] = 0x3F80; ns[2] = ch;     ns[3] = cl; }
    else         { ns[0] = ch;     ns[1] = cl;     ns[2] = 0x3F80; ns[3] = 0x3F80; }

    unsigned short* ph = is_eval ? eh : bh;
    unsigned short* pl = is_eval ? el : bl;
    unsigned short* pn = is_eval ? en : bn;
    uint4* dh = (uint4*)(ph + (size_t)rr * 16);
    uint4* dl = (uint4*)(pl + (size_t)rr * 16);
    uint4* dn = (uint4*)(pn + (size_t)rr * 16);
    dh[0] = pack8(hs); dh[1] = pack8(hs + 8);
    dl[0] = pack8(ls); dl[1] = pack8(ls + 8);
    dn[0] = pack8(ns); dn[1] = pack8(ns + 8);
}

// ---------------------------------------------------------------------------
// main: wave owns ONE 32x32 C tile (32 eval rows) x one base chunk (256 rows).
// 4 waves/block share the chunk -> L1 reuse of A tiles.
__global__ __launch_bounds__(256, 8) void kde_mfma(
        const unsigned short* __restrict__ eh, const unsigned short* __restrict__ el,
        const unsigned short* __restrict__ en,
        const unsigned short* __restrict__ bh, const unsigned short* __restrict__ bl,
        const unsigned short* __restrict__ bn,
        float* __restrict__ part) {
    const int lane = threadIdx.x & 63;
    const int widx = threadIdx.x >> 6;
    const int b = blockIdx.x;                 // 0..4095
    const int chunk = b >> 6;                 // 0..63 (block-uniform)
    const int etp = (b & 63) * 4 + widx;      // 0..255
    const int col = lane & 31;
    const int kg  = lane >> 5;

    // eval (B) fragments — resident for whole kernel
    const size_t eoff = ((size_t)etp * 32 + col) * 16 + (size_t)kg * 8;
    const bf16x8 Bh = *(const bf16x8*)(eh + eoff);
    const bf16x8 Bl = *(const bf16x8*)(el + eoff);
    const bf16x8 Bn = *(const bf16x8*)(en + eoff);

    // base (A): TPC tiles of 32 rows
    size_t aoff = ((size_t)chunk * ROWS_PER_CHUNK + col) * 16 + (size_t)kg * 8;
    const unsigned short* pah = bh + aoff;
    const unsigned short* pal = bl + aoff;
    const unsigned short* pan = bn + aoff;

    float acc0 = 0.f, acc1 = 0.f;

#pragma unroll
    for (int t = 0; t < TPC; ++t) {
        const bf16x8 Ah = *(const bf16x8*)pah;
        const bf16x8 Al = *(const bf16x8*)pal;
        const bf16x8 An = *(const bf16x8*)pan;
        pah += 32 * 16; pal += 32 * 16; pan += 32 * 16;

        f32x16 C;
#pragma unroll
        for (int r = 0; r < 16; ++r) C[r] = 0.f;
        C = __builtin_amdgcn_mfma_f32_32x32x16_bf16(Ah, Bh, C, 0, 0, 0);
        C = __builtin_amdgcn_mfma_f32_32x32x16_bf16(Ah, Bl, C, 0, 0, 0);
        C = __builtin_amdgcn_mfma_f32_32x32x16_bf16(Al, Bh, C, 0, 0, 0);
        C = __builtin_amdgcn_mfma_f32_32x32x16_bf16(An, Bn, C, 0, 0, 0);

#pragma unroll
        for (int r = 0; r < 16; r += 2) {
            acc0 += __builtin_amdgcn_exp2f(C[r]);
            acc1 += __builtin_amdgcn_exp2f(C[r + 1]);
        }
    }

    float s = acc0 + acc1;
    s += __shfl_xor(s, 32, 64);               // fold the two kg row-groups
    if (lane < 32)
        part[(size_t)chunk * M_PTS + (size_t)etp * 32 + col] = s;
}

// ---------------------------------------------------------------------------
__global__ __launch_bounds__(256) void kde_reduce(
        const float* __restrict__ part, const float* __restrict__ log_bw,
        float* __restrict__ out) {
    int m = blockIdx.x * 256 + threadIdx.x;
    if (m >= M_PTS) return;
    float lb = log_bw[0];
    float scale = __expf(-8.f * LOG_2PI_F - lb) / (float)N_PTS;
    float s = 0.f;
#pragma unroll
    for (int c = 0; c < NCH; ++c) s += part[(size_t)c * M_PTS + m];
    out[m] = scale * s;
}

// ---------------------------------------------------------------------------
extern "C" void kernel_launch(void* const* d_in, const int* in_sizes, int n_in,
                              void* d_out, int out_size, void* d_ws, size_t ws_size,
                              hipStream_t stream) {
    const float* xe = (const float*)d_in[0];   // [8192,16]
    const float* xb = (const float*)d_in[1];   // [16384,16]
    const float* lb = (const float*)d_in[2];   // [1]
    float* out = (float*)d_out;                // [8192]

    unsigned short* bh = (unsigned short*)d_ws;
    unsigned short* bl = bh + (size_t)N_PTS * 16;
    unsigned short* bn = bl + (size_t)N_PTS * 16;
    unsigned short* eh = bn + (size_t)N_PTS * 16;
    unsigned short* el = eh + (size_t)M_PTS * 16;
    unsigned short* en = el + (size_t)M_PTS * 16;
    float* part = (float*)(en + (size_t)M_PTS * 16);   // NCH*M_PTS floats (2MB)

    kde_pack<<<(N_PTS + M_PTS) / 256, 256, 0, stream>>>(xe, xb, lb,
                                                        bh, bl, bn, eh, el, en);
    kde_mfma<<<4096, 256, 0, stream>>>(eh, el, en, bh, bl, bn, part);
    kde_reduce<<<M_PTS / 256, 256, 0, stream>>>(part, lb, out);
}